// Round 11
// baseline (861.504 us; speedup 1.0000x reference)
//
#include <hip/hip_runtime.h>
#include <hip/hip_bf16.h>
#include <math.h>

#define CH 64
#define HH 128
#define WW 128
#define HW 16384
#define NVALS 131072.f

// ws layout (float offsets):
//  WEFF2 62208 f | BIAS2 108 f | WTOFF 147456 f | STATS 256 f
//  OACC: ushort region, 3538944 bf16 (offset-conv out, [b][g][j][px])
//  XT:   ushort region, 2097152 bf16 (x transposed, [b][px][c])
#define WEFF2 0
#define BIAS2 62208
#define WTOFF 62464
#define STATS 209920
#define OACC  210176
#define XT    1979648

typedef unsigned short ushort_t;
typedef unsigned int uint_t;

__device__ __forceinline__ float bflo(uint_t u) { return __uint_as_float(u << 16); }
__device__ __forceinline__ float bfhi(uint_t u) { return __uint_as_float(u & 0xFFFF0000u); }
__device__ __forceinline__ float bfu(ushort_t s) { return __uint_as_float(((uint_t)s) << 16); }
__device__ __forceinline__ ushort_t f2bf(float f) {
    __hip_bfloat16 h = __float2bfloat16(f);
    return *(ushort_t*)&h;
}

__device__ __forceinline__ int off_chan(int g, int j) {
    return (j < 18) ? (g * 18 + j) : (72 + g * 9 + (j - 18));
}

__global__ void prep(const float* __restrict__ w_offset, const float* __restrict__ b_offset,
                     const float* __restrict__ w_dcn, float* __restrict__ ws) {
    int tid = blockIdx.x * 256 + threadIdx.x;
    if (tid < 147456) {
        int o = tid & 63;
        int k = (tid >> 6) % 9;
        int c = (tid / 576) & 63;
        int g = tid / 36864;
        ws[WTOFF + tid] = w_dcn[((g * 64 + o) * 64 + c) * 9 + k];
    }
    if (tid < 62208) {
        int j = tid % 27;
        int r = tid / 27;
        int k = r % 9;
        int gc = r / 9;
        int c = gc & 63;
        int g = gc >> 6;
        int o = off_chan(g, j);
        float s = 0.f;
#pragma unroll
        for (int ss = 0; ss < 4; ++ss)
            s += w_offset[(o * 256 + ss * 64 + c) * 9 + k];
        ws[WEFF2 + tid] = s;
    }
    if (tid < 108) {
        int g = tid / 27, j = tid % 27;
        ws[BIAS2 + tid] = b_offset[off_chan(g, j)];
    }
    if (tid < 128) ws[STATS + tid] = 0.f;
}

// x [b][c][px] f32 -> xT [b][px][c] bf16.  grid 512 (b*256 + tile of 64 px)
__global__ __launch_bounds__(256) void transpose_x(const float* __restrict__ x,
                                                   ushort_t* __restrict__ xT) {
    int b = blockIdx.x >> 8;
    int px0 = (blockIdx.x & 255) << 6;
    __shared__ float lds[64][65];
    int t = threadIdx.x;
    int lx = t & 63;
    int row = t >> 6;
    const float* xb = x + (size_t)b * CH * HW;
#pragma unroll
    for (int i = 0; i < 16; ++i) {
        int c = i * 4 + row;
        lds[c][lx] = xb[(size_t)c * HW + px0 + lx];
    }
    __syncthreads();
    ushort_t* dst = xT + ((size_t)b * HW + px0) * 64;
#pragma unroll
    for (int i = 0; i < 16; ++i) {
        int p = i * 4 + row;
        dst[(size_t)p * 64 + lx] = f2bf(lds[lx][p]);
    }
}

// single offset-conv kernel, channel-last bf16 input.  flat grid 512.
// xcd = blk&7 -> (b = xcd>>2, quad = xcd&3); unit = blk>>3: tl = unit&15, g = unit>>4
__global__ __launch_bounds__(256, 2) void conv_off(const ushort_t* __restrict__ xT,
                                                   const float* __restrict__ ws,
                                                   ushort_t* __restrict__ oaccb) {
    int blk = blockIdx.x;
    int xcd = blk & 7;
    int b = xcd >> 2;
    int quad = xcd & 3;
    int unit = blk >> 3;
    int tl = unit & 15;
    int g = unit >> 4;
    int th = quad * 2 + (tl >> 3);
    int tw = tl & 7;
    int t = threadIdx.x;
    int h = th * 16 + (t >> 4);
    int w = tw * 16 + (t & 15);
    const ushort_t* xTb = xT + (size_t)b * HW * 64;

    float oacc[27];
    const float* bp = ws + BIAS2 + g * 27;
#pragma unroll
    for (int j = 0; j < 27; ++j) oacc[j] = bp[j];

    int offs[9];
    float vmask[9];
#pragma unroll
    for (int k = 0; k < 9; ++k) {
        int yy = h + k / 3 - 1, xx = w + k % 3 - 1;
        bool v = (yy >= 0) && (yy < HH) && (xx >= 0) && (xx < WW);
        vmask[k] = v ? 1.f : 0.f;
        offs[k] = min(max(yy, 0), HH - 1) * WW + min(max(xx, 0), WW - 1);
    }

    const float* wg = ws + WEFF2 + (g * 64) * 243;   // [c][k][j], j contiguous

    // 18 half-tap steps: step s -> tap k=s>>1, channel-half hh=s&1 (32 ch = 4 uint4)
    uint4 qa[4], qb[4];
#define HLOAD(Q, s_)                                                         \
    {                                                                        \
        const int k_ = (s_) >> 1, hh_ = (s_) & 1;                            \
        const uint4* p_ = (const uint4*)(xTb + (size_t)offs[k_] * 64) + hh_ * 4; \
        Q[0] = p_[0]; Q[1] = p_[1]; Q[2] = p_[2]; Q[3] = p_[3];              \
    }
#define HFMA(Q, s_)                                                          \
    {                                                                        \
        const int k_ = (s_) >> 1, hh_ = (s_) & 1;                            \
        float vm_ = vmask[k_];                                               \
        const float* wk_ = wg + (hh_ * 32) * 243 + k_ * 27;                  \
        _Pragma("unroll") for (int qi = 0; qi < 4; ++qi) {                   \
            uint_t uu_[4] = {Q[qi].x, Q[qi].y, Q[qi].z, Q[qi].w};            \
            _Pragma("unroll") for (int e = 0; e < 4; ++e) {                  \
                int c_ = qi * 8 + e * 2;                                     \
                float xlo_ = bflo(uu_[e]) * vm_;                             \
                float xhi_ = bfhi(uu_[e]) * vm_;                             \
                const float* wl_ = wk_ + c_ * 243;                           \
                _Pragma("unroll") for (int j = 0; j < 27; ++j)               \
                    oacc[j] = fmaf(xlo_, wl_[j], oacc[j]);                   \
                _Pragma("unroll") for (int j = 0; j < 27; ++j)               \
                    oacc[j] = fmaf(xhi_, wl_[j + 243], oacc[j]);             \
            }                                                                \
        }                                                                    \
    }
    HLOAD(qa, 0);
#pragma unroll
    for (int s = 0; s < 18; s += 2) {
        HLOAD(qb, s + 1);
        HFMA(qa, s);
        if (s + 2 < 18) HLOAD(qa, s + 2);
        HFMA(qb, s + 1);
    }
#undef HLOAD
#undef HFMA

    ushort_t* op = oaccb + (size_t)((b * 4 + g) * 27) * HW + h * WW + w;
#pragma unroll
    for (int j = 0; j < 27; ++j) op[(size_t)j * HW] = f2bf(oacc[j]);
}

// deformable conv, o-chunked (32/block), channel-last bf16 gathers. NO atomics.
__global__ __launch_bounds__(256, 2) void dcn(const float* __restrict__ ws_f,
                                              const ushort_t* __restrict__ xT,
                                              const ushort_t* __restrict__ oaccb,
                                              float* __restrict__ out) {
    int blk = blockIdx.x;
    int xcd = blk & 7;
    int b = xcd >> 2;
    int quad = xcd & 3;
    int unit = blk >> 3;
    int tl = unit & 15;
    int go = unit >> 4;
    int g = go & 3;
    int obase = (go >> 2) * 32;
    int th = quad * 2 + (tl >> 3);
    int tw = tl & 7;
    int t = threadIdx.x;
    int h = th * 16 + (t >> 4);
    int w = tw * 16 + (t & 15);
    int px = h * WW + w;
    const ushort_t* xTb = xT + (size_t)b * HW * 64;
    const ushort_t* ob_in = oaccb + (size_t)(b * 4 + g) * 27 * HW + px;

    float acc[32];
#pragma unroll
    for (int o = 0; o < 32; ++o) acc[o] = 0.f;

    const float* wg = ws_f + WTOFF + g * 36864 + obase;

    for (int k = 0; k < 9; ++k) {
        float dy = bfu(ob_in[(size_t)(2 * k) * HW]);
        float dx = bfu(ob_in[(size_t)(2 * k + 1) * HW]);
        float mk = 1.f / (1.f + expf(-bfu(ob_in[(size_t)(18 + k) * HW])));

        float py = (float)h + (float)(k / 3 - 1) + dy;
        float qx = (float)w + (float)(k % 3 - 1) + dx;
        float y0f = floorf(py), x0f = floorf(qx);
        float ly = py - y0f, lx = qx - x0f;
        int y0 = (int)y0f, x0 = (int)x0f;
        int y1 = y0 + 1, x1 = x0 + 1;

        bool vy0 = (y0 >= 0) && (y0 < HH), vy1 = (y1 >= 0) && (y1 < HH);
        bool vx0 = (x0 >= 0) && (x0 < WW), vx1 = (x1 >= 0) && (x1 < WW);
        int yc0 = min(max(y0, 0), HH - 1), yc1 = min(max(y1, 0), HH - 1);
        int xc0 = min(max(x0, 0), WW - 1), xc1 = min(max(x1, 0), WW - 1);
        int i00 = yc0 * WW + xc0, i01 = yc0 * WW + xc1;
        int i10 = yc1 * WW + xc0, i11 = yc1 * WW + xc1;

        float w00 = (1.f - ly) * (1.f - lx) * mk * ((vy0 && vx0) ? 1.f : 0.f);
        float w01 = (1.f - ly) * lx * mk * ((vy0 && vx1) ? 1.f : 0.f);
        float w10 = ly * (1.f - lx) * mk * ((vy1 && vx0) ? 1.f : 0.f);
        float w11 = ly * lx * mk * ((vy1 && vx1) ? 1.f : 0.f);

        const uint4* p00 = (const uint4*)(xTb + (size_t)i00 * 64);
        const uint4* p01 = (const uint4*)(xTb + (size_t)i01 * 64);
        const uint4* p10 = (const uint4*)(xTb + (size_t)i10 * 64);
        const uint4* p11 = (const uint4*)(xTb + (size_t)i11 * 64);
        const float* wk = wg + k * 64;

#define DOCH(U00, U01, U10, U11, CB)                                        \
    {                                                                       \
        float a00 = bflo(U00), a01 = bflo(U01), a10 = bflo(U10),            \
              a11 = bflo(U11);                                              \
        float col = w00 * a00 + w01 * a01 + w10 * a10 + w11 * a11;          \
        const float* wp = wk + (CB)*576;                                    \
        _Pragma("unroll") for (int o = 0; o < 32; ++o)                      \
            acc[o] = fmaf(col, wp[o], acc[o]);                              \
        a00 = bfhi(U00); a01 = bfhi(U01); a10 = bfhi(U10); a11 = bfhi(U11); \
        col = w00 * a00 + w01 * a01 + w10 * a10 + w11 * a11;                \
        wp = wk + ((CB) + 1) * 576;                                         \
        _Pragma("unroll") for (int o = 0; o < 32; ++o)                      \
            acc[o] = fmaf(col, wp[o], acc[o]);                              \
    }
#define LOADQ(D, CG) { D[0] = p00[CG]; D[1] = p01[CG]; D[2] = p10[CG]; D[3] = p11[CG]; }
#define FMAQ(S, C0)                                  \
    DOCH(S[0].x, S[1].x, S[2].x, S[3].x, (C0) + 0);  \
    DOCH(S[0].y, S[1].y, S[2].y, S[3].y, (C0) + 2);  \
    DOCH(S[0].z, S[1].z, S[2].z, S[3].z, (C0) + 4);  \
    DOCH(S[0].w, S[1].w, S[2].w, S[3].w, (C0) + 6);

        uint4 xa[4], xb2[4];
        LOADQ(xa, 0);
#pragma unroll
        for (int cg = 0; cg < 8; cg += 2) {
            LOADQ(xb2, cg + 1);
            FMAQ(xa, cg * 8);
            if (cg + 2 < 8) LOADQ(xa, cg + 2);
            FMAQ(xb2, (cg + 1) * 8);
        }
#undef DOCH
#undef LOADQ
#undef FMAQ
    }

    int h2 = h * 2 + (g >> 1), w2 = w * 2 + (g & 1);
    float* op = out + (size_t)b * 64 * 65536 + (size_t)obase * 65536
              + (size_t)h2 * 256 + w2;
#pragma unroll
    for (int o = 0; o < 32; ++o)
        op[(size_t)o * 65536] = acc[o];
}

// per-channel sum/sumsq over out (pre-norm).  grid 64 (one block per channel).
__global__ __launch_bounds__(256) void stats_sum(const float* __restrict__ out,
                                                 float* __restrict__ stats) {
    int o = blockIdx.x;
    int t = threadIdx.x;
    float s = 0.f, s2 = 0.f;
#pragma unroll
    for (int b = 0; b < 2; ++b) {
        const float* p = out + (size_t)b * 64 * 65536 + (size_t)o * 65536;
        for (int i = t * 4; i < 65536; i += 1024) {
            float4 v = *(const float4*)(p + i);
            s += v.x + v.y + v.z + v.w;
            s2 += v.x * v.x + v.y * v.y + v.z * v.z + v.w * v.w;
        }
    }
    __shared__ float red[512];
    red[t] = s;
    red[256 + t] = s2;
    __syncthreads();
#pragma unroll
    for (int m = 128; m >= 1; m >>= 1) {
        if (t < m) {
            red[t] += red[t + m];
            red[256 + t] += red[256 + t + m];
        }
        __syncthreads();
    }
    if (t == 0) {
        stats[o] = red[0];
        stats[64 + o] = red[256];
    }
}

__global__ void finalize(const float* __restrict__ stats,
                         const float* __restrict__ gamma,
                         const float* __restrict__ beta,
                         float* __restrict__ ab) {
    int t = threadIdx.x;
    if (t < 64) {
        float mean = stats[t] / NVALS;
        float var = stats[64 + t] / NVALS - mean * mean;
        var = fmaxf(var, 0.f);
        float a = gamma[t] * rsqrtf(var + 1e-5f);
        ab[t] = a;
        ab[64 + t] = beta[t] - mean * a;
    }
}

__global__ void norm_relu(float* __restrict__ out, const float* __restrict__ ab) {
    size_t tid = (size_t)blockIdx.x * 256 + threadIdx.x;
    size_t base = tid * 4;
    int o = (int)((base >> 16) & 63);
    float a = ab[o], bb = ab[64 + o];
    float4* p = (float4*)(out + base);
    float4 v = *p;
    v.x = fmaxf(fmaf(v.x, a, bb), 0.f);
    v.y = fmaxf(fmaf(v.y, a, bb), 0.f);
    v.z = fmaxf(fmaf(v.z, a, bb), 0.f);
    v.w = fmaxf(fmaf(v.w, a, bb), 0.f);
    *p = v;
}

extern "C" void kernel_launch(void* const* d_in, const int* in_sizes, int n_in,
                              void* d_out, int out_size, void* d_ws, size_t ws_size,
                              hipStream_t stream) {
    const float* x        = (const float*)d_in[0];
    const float* w_offset = (const float*)d_in[1];
    const float* b_offset = (const float*)d_in[2];
    const float* w_dcn    = (const float*)d_in[3];
    const float* gamma    = (const float*)d_in[4];
    const float* beta     = (const float*)d_in[5];
    float* out            = (float*)d_out;
    float* ws = (float*)d_ws;

    prep<<<576, 256, 0, stream>>>(w_offset, b_offset, w_dcn, ws);
    transpose_x<<<512, 256, 0, stream>>>(x, (ushort_t*)(ws + XT));
    conv_off<<<512, 256, 0, stream>>>((ushort_t*)(ws + XT), ws, (ushort_t*)(ws + OACC));
    dcn<<<1024, 256, 0, stream>>>(ws, (ushort_t*)(ws + XT), (ushort_t*)(ws + OACC), out);
    stats_sum<<<64, 256, 0, stream>>>(out, ws + STATS);
    finalize<<<1, 64, 0, stream>>>(ws + STATS, gamma, beta, ws + STATS + 128);
    norm_relu<<<8192, 256, 0, stream>>>(out, ws + STATS + 128);
}

// Round 12
// 357.478 us; speedup vs baseline: 2.4099x; 2.4099x over previous
//
#include <hip/hip_runtime.h>
#include <hip/hip_bf16.h>
#include <math.h>

#define CH 64
#define HH 128
#define WW 128
#define HW 16384
#define NVALS 131072.f

// ws layout (float offsets):
//  [unused legacy 62208] | BIAS2 108 f (bias, m=g*27+j order) | WTOFF 147456 f |
//  STATS 256 f | OACC ushort 3538944 (conv out bf16, [b][m][px]) |
//  XT ushort 2097152 (x channel-last bf16) | WAFRAG ushort 64512 (MFMA A-frags)
#define BIAS2 62208
#define WTOFF 62464
#define STATS 209920
#define OACC  210176
#define XT    1979648
#define WAFRAG 3028224

typedef unsigned short ushort_t;
typedef unsigned int uint_t;
typedef __attribute__((ext_vector_type(8))) short bf16x8;
typedef __attribute__((ext_vector_type(4))) float f32x4;

__device__ __forceinline__ float bflo(uint_t u) { return __uint_as_float(u << 16); }
__device__ __forceinline__ float bfhi(uint_t u) { return __uint_as_float(u & 0xFFFF0000u); }
__device__ __forceinline__ float bfu(ushort_t s) { return __uint_as_float(((uint_t)s) << 16); }
__device__ __forceinline__ ushort_t f2bf(float f) {
    __hip_bfloat16 h = __float2bfloat16(f);
    return *(ushort_t*)&h;
}

__device__ __forceinline__ int off_chan(int g, int j) {
    return (j < 18) ? (g * 18 + j) : (72 + g * 9 + (j - 18));
}

__global__ void prep(const float* __restrict__ w_offset, const float* __restrict__ b_offset,
                     const float* __restrict__ w_dcn, float* __restrict__ ws) {
    int tid = blockIdx.x * 256 + threadIdx.x;
    if (tid < 147456) {
        int o = tid & 63;
        int k = (tid >> 6) % 9;
        int c = (tid / 576) & 63;
        int g = tid / 36864;
        ws[WTOFF + tid] = w_dcn[((g * 64 + o) * 64 + c) * 9 + k];
    }
    if (tid < 64512) {   // conv MFMA A-fragments: ((kt*7+mt)*64+lane)*8+jp
        int jp = tid & 7;
        int lane = (tid >> 3) & 63;
        int rest = tid >> 9;          // kt*7 + mt
        int mt = rest % 7;
        int kt = rest / 7;
        int m = mt * 16 + (lane & 15);
        int off = ((lane >> 4) << 3) + jp;      // [0,32)
        int c = ((kt & 1) << 5) + off;
        int k = kt >> 1;
        float s = 0.f;
        if (m < 108) {
            int och = off_chan(m / 27, m % 27);
#pragma unroll
            for (int ss = 0; ss < 4; ++ss)
                s += w_offset[(och * 256 + ss * 64 + c) * 9 + k];
        }
        ((ushort_t*)(ws + WAFRAG))[tid] = f2bf(s);
    }
    if (tid < 108) ws[BIAS2 + tid] = b_offset[off_chan(tid / 27, tid % 27)];
    if (tid < 128) ws[STATS + tid] = 0.f;
}

// x [b][c][px] f32 -> xT [b][px][c] bf16.  grid 512 (b*256 + tile of 64 px)
__global__ __launch_bounds__(256) void transpose_x(const float* __restrict__ x,
                                                   ushort_t* __restrict__ xT) {
    int b = blockIdx.x >> 8;
    int px0 = (blockIdx.x & 255) << 6;
    __shared__ float lds[64][65];
    int t = threadIdx.x;
    int lx = t & 63;
    int row = t >> 6;
    const float* xb = x + (size_t)b * CH * HW;
#pragma unroll
    for (int i = 0; i < 16; ++i) {
        int c = i * 4 + row;
        lds[c][lx] = xb[(size_t)c * HW + px0 + lx];
    }
    __syncthreads();
    ushort_t* dst = xT + ((size_t)b * HW + px0) * 64;
#pragma unroll
    for (int i = 0; i < 16; ++i) {
        int p = i * 4 + row;
        dst[(size_t)p * 64 + lx] = f2bf(lds[lx][p]);
    }
}

// offset conv as MFMA implicit GEMM: out[108][px] = W[108][576] * col[576][px].
// grid 256 = b*128 + tile (tile: 16 slabs of 8 rows x 8 cols of 16).  4 waves.
// M: 7 tiles of 16 (108 pad 112); N per wave: 2 tiles of 16 px; K: 18 tiles of 32.
__global__ __launch_bounds__(256, 2) void conv_mfma(const ushort_t* __restrict__ xT,
                                                    const ushort_t* __restrict__ wA,
                                                    const float* __restrict__ biasM,
                                                    ushort_t* __restrict__ oaccb) {
    int blk = blockIdx.x;
    int b = blk >> 7;
    int tile = blk & 127;
    int th = tile >> 3, tw = tile & 7;
    int t = threadIdx.x;
    int wv = t >> 6, lane = t & 63;
    int lw = lane & 15, kg = lane >> 4;

    // halo tile: 10 rows x 18 cols of 64-ch bf16 rows, padded to 72 ushort/row
    __shared__ ushort_t lds[180 * 72];

    const ushort_t* xTb = xT + (size_t)b * HW * 64;
    for (int rr = t; rr < 180; rr += 256) {
        int r = rr / 18, c2 = rr - r * 18;
        int hy = th * 8 + r - 1, wx = tw * 16 + c2 - 1;
        bool valid = (hy >= 0) && (hy < HH) && (wx >= 0) && (wx < WW);
        uint4* dst = (uint4*)&lds[rr * 72];
        if (valid) {
            const uint4* src = (const uint4*)(xTb + ((size_t)(hy * WW + wx)) * 64);
#pragma unroll
            for (int ch = 0; ch < 8; ++ch) dst[ch] = src[ch];
        } else {
            uint4 z; z.x = z.y = z.z = z.w = 0;
#pragma unroll
            for (int ch = 0; ch < 8; ++ch) dst[ch] = z;
        }
    }
    __syncthreads();

    f32x4 acc[7][2];
#pragma unroll
    for (int mt = 0; mt < 7; ++mt)
#pragma unroll
        for (int i = 0; i < 2; ++i)
            acc[mt][i] = (f32x4){0.f, 0.f, 0.f, 0.f};

    const bf16x8* wAv = (const bf16x8*)wA;
    for (int kt = 0; kt < 18; ++kt) {
        int k = kt >> 1;
        int dh = k / 3, dw = k - dh * 3;     // 0..2 (halo origin already -1)
        int hh = kt & 1;
        bf16x8 bfrag[2];
#pragma unroll
        for (int i = 0; i < 2; ++i) {
            int nt = wv * 2 + i;
            int rr = (nt + dh) * 18 + lw + dw;
            bfrag[i] = *(const bf16x8*)&lds[rr * 72 + ((hh << 2) + kg) * 8];
        }
        bf16x8 afrag[7];
#pragma unroll
        for (int mt = 0; mt < 7; ++mt)
            afrag[mt] = wAv[(kt * 7 + mt) * 64 + lane];
#pragma unroll
        for (int mt = 0; mt < 7; ++mt)
#pragma unroll
            for (int i = 0; i < 2; ++i)
                acc[mt][i] = __builtin_amdgcn_mfma_f32_16x16x32_bf16(
                    afrag[mt], bfrag[i], acc[mt][i], 0, 0, 0);
    }

    // C/D: col = lane&15 (px), row = kg*4 + reg (m within tile)
#pragma unroll
    for (int mt = 0; mt < 7; ++mt) {
#pragma unroll
        for (int r = 0; r < 4; ++r) {
            int m = mt * 16 + (kg << 2) + r;
            if (m < 108) {
                float bia = biasM[m];
#pragma unroll
                for (int i = 0; i < 2; ++i) {
                    int hgl = th * 8 + wv * 2 + i;
                    int wgl = tw * 16 + lw;
                    oaccb[((size_t)b * 108 + m) * HW + hgl * WW + wgl] =
                        f2bf(acc[mt][i][r] + bia);
                }
            }
        }
    }
}

// deformable conv, o-chunked (32/block), channel-last bf16 gathers. NO atomics.
__global__ __launch_bounds__(256, 2) void dcn(const float* __restrict__ ws_f,
                                              const ushort_t* __restrict__ xT,
                                              const ushort_t* __restrict__ oaccb,
                                              float* __restrict__ out) {
    int blk = blockIdx.x;
    int xcd = blk & 7;
    int b = xcd >> 2;
    int quad = xcd & 3;
    int unit = blk >> 3;
    int tl = unit & 15;
    int go = unit >> 4;
    int g = go & 3;
    int obase = (go >> 2) * 32;
    int th = quad * 2 + (tl >> 3);
    int tw = tl & 7;
    int t = threadIdx.x;
    int h = th * 16 + (t >> 4);
    int w = tw * 16 + (t & 15);
    int px = h * WW + w;
    const ushort_t* xTb = xT + (size_t)b * HW * 64;
    const ushort_t* ob_in = oaccb + (size_t)(b * 4 + g) * 27 * HW + px;

    float acc[32];
#pragma unroll
    for (int o = 0; o < 32; ++o) acc[o] = 0.f;

    const float* wg = ws_f + WTOFF + g * 36864 + obase;

    for (int k = 0; k < 9; ++k) {
        float dy = bfu(ob_in[(size_t)(2 * k) * HW]);
        float dx = bfu(ob_in[(size_t)(2 * k + 1) * HW]);
        float mk = 1.f / (1.f + expf(-bfu(ob_in[(size_t)(18 + k) * HW])));

        float py = (float)h + (float)(k / 3 - 1) + dy;
        float qx = (float)w + (float)(k % 3 - 1) + dx;
        float y0f = floorf(py), x0f = floorf(qx);
        float ly = py - y0f, lx = qx - x0f;
        int y0 = (int)y0f, x0 = (int)x0f;
        int y1 = y0 + 1, x1 = x0 + 1;

        bool vy0 = (y0 >= 0) && (y0 < HH), vy1 = (y1 >= 0) && (y1 < HH);
        bool vx0 = (x0 >= 0) && (x0 < WW), vx1 = (x1 >= 0) && (x1 < WW);
        int yc0 = min(max(y0, 0), HH - 1), yc1 = min(max(y1, 0), HH - 1);
        int xc0 = min(max(x0, 0), WW - 1), xc1 = min(max(x1, 0), WW - 1);
        int i00 = yc0 * WW + xc0, i01 = yc0 * WW + xc1;
        int i10 = yc1 * WW + xc0, i11 = yc1 * WW + xc1;

        float w00 = (1.f - ly) * (1.f - lx) * mk * ((vy0 && vx0) ? 1.f : 0.f);
        float w01 = (1.f - ly) * lx * mk * ((vy0 && vx1) ? 1.f : 0.f);
        float w10 = ly * (1.f - lx) * mk * ((vy1 && vx0) ? 1.f : 0.f);
        float w11 = ly * lx * mk * ((vy1 && vx1) ? 1.f : 0.f);

        const uint4* p00 = (const uint4*)(xTb + (size_t)i00 * 64);
        const uint4* p01 = (const uint4*)(xTb + (size_t)i01 * 64);
        const uint4* p10 = (const uint4*)(xTb + (size_t)i10 * 64);
        const uint4* p11 = (const uint4*)(xTb + (size_t)i11 * 64);
        const float* wk = wg + k * 64;

#define DOCH(U00, U01, U10, U11, CB)                                        \
    {                                                                       \
        float a00 = bflo(U00), a01 = bflo(U01), a10 = bflo(U10),            \
              a11 = bflo(U11);                                              \
        float col = w00 * a00 + w01 * a01 + w10 * a10 + w11 * a11;          \
        const float* wp = wk + (CB)*576;                                    \
        _Pragma("unroll") for (int o = 0; o < 32; ++o)                      \
            acc[o] = fmaf(col, wp[o], acc[o]);                              \
        a00 = bfhi(U00); a01 = bfhi(U01); a10 = bfhi(U10); a11 = bfhi(U11); \
        col = w00 * a00 + w01 * a01 + w10 * a10 + w11 * a11;                \
        wp = wk + ((CB) + 1) * 576;                                         \
        _Pragma("unroll") for (int o = 0; o < 32; ++o)                      \
            acc[o] = fmaf(col, wp[o], acc[o]);                              \
    }
#define LOADQ(D, CG) { D[0] = p00[CG]; D[1] = p01[CG]; D[2] = p10[CG]; D[3] = p11[CG]; }
#define FMAQ(S, C0)                                  \
    DOCH(S[0].x, S[1].x, S[2].x, S[3].x, (C0) + 0);  \
    DOCH(S[0].y, S[1].y, S[2].y, S[3].y, (C0) + 2);  \
    DOCH(S[0].z, S[1].z, S[2].z, S[3].z, (C0) + 4);  \
    DOCH(S[0].w, S[1].w, S[2].w, S[3].w, (C0) + 6);

        uint4 xa[4], xb2[4];
        LOADQ(xa, 0);
#pragma unroll
        for (int cg = 0; cg < 8; cg += 2) {
            LOADQ(xb2, cg + 1);
            FMAQ(xa, cg * 8);
            if (cg + 2 < 8) LOADQ(xa, cg + 2);
            FMAQ(xb2, (cg + 1) * 8);
        }
#undef DOCH
#undef LOADQ
#undef FMAQ
    }

    int h2 = h * 2 + (g >> 1), w2 = w * 2 + (g & 1);
    float* op = out + (size_t)b * 64 * 65536 + (size_t)obase * 65536
              + (size_t)h2 * 256 + w2;
#pragma unroll
    for (int o = 0; o < 32; ++o)
        op[(size_t)o * 65536] = acc[o];
}

// per-channel sum/sumsq over out (pre-norm).  grid 64 (one block per channel).
__global__ __launch_bounds__(256) void stats_sum(const float* __restrict__ out,
                                                 float* __restrict__ stats) {
    int o = blockIdx.x;
    int t = threadIdx.x;
    float s = 0.f, s2 = 0.f;
#pragma unroll
    for (int b = 0; b < 2; ++b) {
        const float* p = out + (size_t)b * 64 * 65536 + (size_t)o * 65536;
        for (int i = t * 4; i < 65536; i += 1024) {
            float4 v = *(const float4*)(p + i);
            s += v.x + v.y + v.z + v.w;
            s2 += v.x * v.x + v.y * v.y + v.z * v.z + v.w * v.w;
        }
    }
    __shared__ float red[512];
    red[t] = s;
    red[256 + t] = s2;
    __syncthreads();
#pragma unroll
    for (int m = 128; m >= 1; m >>= 1) {
        if (t < m) {
            red[t] += red[t + m];
            red[256 + t] += red[256 + t + m];
        }
        __syncthreads();
    }
    if (t == 0) {
        stats[o] = red[0];
        stats[64 + o] = red[256];
    }
}

__global__ void finalize(const float* __restrict__ stats,
                         const float* __restrict__ gamma,
                         const float* __restrict__ beta,
                         float* __restrict__ ab) {
    int t = threadIdx.x;
    if (t < 64) {
        float mean = stats[t] / NVALS;
        float var = stats[64 + t] / NVALS - mean * mean;
        var = fmaxf(var, 0.f);
        float a = gamma[t] * rsqrtf(var + 1e-5f);
        ab[t] = a;
        ab[64 + t] = beta[t] - mean * a;
    }
}

__global__ void norm_relu(float* __restrict__ out, const float* __restrict__ ab) {
    size_t tid = (size_t)blockIdx.x * 256 + threadIdx.x;
    size_t base = tid * 4;
    int o = (int)((base >> 16) & 63);
    float a = ab[o], bb = ab[64 + o];
    float4* p = (float4*)(out + base);
    float4 v = *p;
    v.x = fmaxf(fmaf(v.x, a, bb), 0.f);
    v.y = fmaxf(fmaf(v.y, a, bb), 0.f);
    v.z = fmaxf(fmaf(v.z, a, bb), 0.f);
    v.w = fmaxf(fmaf(v.w, a, bb), 0.f);
    *p = v;
}

extern "C" void kernel_launch(void* const* d_in, const int* in_sizes, int n_in,
                              void* d_out, int out_size, void* d_ws, size_t ws_size,
                              hipStream_t stream) {
    const float* x        = (const float*)d_in[0];
    const float* w_offset = (const float*)d_in[1];
    const float* b_offset = (const float*)d_in[2];
    const float* w_dcn    = (const float*)d_in[3];
    const float* gamma    = (const float*)d_in[4];
    const float* beta     = (const float*)d_in[5];
    float* out            = (float*)d_out;
    float* ws = (float*)d_ws;

    prep<<<576, 256, 0, stream>>>(w_offset, b_offset, w_dcn, ws);
    transpose_x<<<512, 256, 0, stream>>>(x, (ushort_t*)(ws + XT));
    conv_mfma<<<256, 256, 0, stream>>>((ushort_t*)(ws + XT), (ushort_t*)(ws + WAFRAG),
                                       ws + BIAS2, (ushort_t*)(ws + OACC));
    dcn<<<1024, 256, 0, stream>>>(ws, (ushort_t*)(ws + XT), (ushort_t*)(ws + OACC), out);
    stats_sum<<<64, 256, 0, stream>>>(out, ws + STATS);
    finalize<<<1, 64, 0, stream>>>(ws + STATS, gamma, beta, ws + STATS + 128);
    norm_relu<<<8192, 256, 0, stream>>>(out, ws + STATS + 128);
}

// Round 13
// 166.793 us; speedup vs baseline: 5.1651x; 2.1432x over previous
//
#include <hip/hip_runtime.h>
#include <hip/hip_bf16.h>
#include <math.h>

#define CH 64
#define HH 128
#define WW 128
#define HW 16384
#define NVALS 131072.f

// ws layout (float offsets):
//  STATS 0 (256 f: sum64, sumsq64, ab128) | BIAS2 256 (108 f, pad->384)
//  WACONV 384 (64512 ushort = 32256 f)    | WADCN 32640 (147456 ushort = 73728 f)
//  OACC 106368 (3538944 ushort bf16, [b][m=g*27+j][px])
//  XT 1875840 (2097152 ushort bf16, [b][px][c])   total 11.7 MB
#define STATS  0
#define BIAS2  256
#define WACONV 384
#define WADCN  32640
#define OACC   106368
#define XT     1875840

typedef unsigned short ushort_t;
typedef unsigned int uint_t;
typedef __attribute__((ext_vector_type(8))) short bf16x8;
typedef __attribute__((ext_vector_type(4))) float f32x4;

__device__ __forceinline__ float bflo(uint_t u) { return __uint_as_float(u << 16); }
__device__ __forceinline__ float bfhi(uint_t u) { return __uint_as_float(u & 0xFFFF0000u); }
__device__ __forceinline__ float bfu(ushort_t s) { return __uint_as_float(((uint_t)s) << 16); }
__device__ __forceinline__ ushort_t f2bf(float f) {
    __hip_bfloat16 h = __float2bfloat16(f);
    return *(ushort_t*)&h;
}
__device__ __forceinline__ uint_t pack2(float lo, float hi) {
    return (uint_t)f2bf(lo) | ((uint_t)f2bf(hi) << 16);
}

__device__ __forceinline__ int off_chan(int g, int j) {
    return (j < 18) ? (g * 18 + j) : (72 + g * 9 + (j - 18));
}

__global__ void prep(const float* __restrict__ w_offset, const float* __restrict__ b_offset,
                     const float* __restrict__ w_dcn, float* __restrict__ ws) {
    int tid = blockIdx.x * 256 + threadIdx.x;
    if (tid < 64512) {   // conv MFMA A-frags: ((kt*7+mt)*64+lane)*8+jp
        int jp = tid & 7;
        int lane = (tid >> 3) & 63;
        int rest = tid >> 9;
        int mt = rest % 7;
        int kt = rest / 7;
        int m = mt * 16 + (lane & 15);
        int off = ((lane >> 4) << 3) + jp;
        int c = ((kt & 1) << 5) + off;
        int k = kt >> 1;
        float s = 0.f;
        if (m < 108) {
            int och = off_chan(m / 27, m % 27);
#pragma unroll
            for (int ss = 0; ss < 4; ++ss)
                s += w_offset[(och * 256 + ss * 64 + c) * 9 + k];
        }
        ((ushort_t*)(ws + WACONV))[tid] = f2bf(s);
    }
    if (tid < 147456) {  // dcn MFMA A-frags: (((g*18+kt)*4+mt)*64+lane)*8+jp
        int jp = tid & 7;
        int lane = (tid >> 3) & 63;
        int q = tid >> 9;            // ((g*18+kt)*4+mt)
        int mt = q & 3;
        int kt = (q >> 2) % 18;
        int g = q / 72;
        int m = mt * 16 + (lane & 15);
        int c = ((kt & 1) << 5) + ((lane >> 4) << 3) + jp;
        int tap = kt >> 1;
        ((ushort_t*)(ws + WADCN))[tid] = f2bf(w_dcn[((g * 64 + m) * 64 + c) * 9 + tap]);
    }
    if (tid < 108) ws[BIAS2 + tid] = b_offset[off_chan(tid / 27, tid % 27)];
    if (tid < 128) ws[STATS + tid] = 0.f;
}

// x [b][c][px] f32 -> xT [b][px][c] bf16.  grid 512
__global__ __launch_bounds__(256) void transpose_x(const float* __restrict__ x,
                                                   ushort_t* __restrict__ xT) {
    int b = blockIdx.x >> 8;
    int px0 = (blockIdx.x & 255) << 6;
    __shared__ float lds[64][65];
    int t = threadIdx.x;
    int lx = t & 63;
    int row = t >> 6;
    const float* xb = x + (size_t)b * CH * HW;
#pragma unroll
    for (int i = 0; i < 16; ++i) {
        int c = i * 4 + row;
        lds[c][lx] = xb[(size_t)c * HW + px0 + lx];
    }
    __syncthreads();
    ushort_t* dst = xT + ((size_t)b * HW + px0) * 64;
#pragma unroll
    for (int i = 0; i < 16; ++i) {
        int p = i * 4 + row;
        dst[(size_t)p * 64 + lx] = f2bf(lds[lx][p]);
    }
}

// offset conv as MFMA implicit GEMM (validated round 12).
__global__ __launch_bounds__(256, 2) void conv_mfma(const ushort_t* __restrict__ xT,
                                                    const ushort_t* __restrict__ wA,
                                                    const float* __restrict__ biasM,
                                                    ushort_t* __restrict__ oaccb) {
    int blk = blockIdx.x;
    int b = blk >> 7;
    int tile = blk & 127;
    int th = tile >> 3, tw = tile & 7;
    int t = threadIdx.x;
    int wv = t >> 6, lane = t & 63;
    int lw = lane & 15, kg = lane >> 4;

    __shared__ ushort_t lds[180 * 72];

    const ushort_t* xTb = xT + (size_t)b * HW * 64;
    for (int rr = t; rr < 180; rr += 256) {
        int r = rr / 18, c2 = rr - r * 18;
        int hy = th * 8 + r - 1, wx = tw * 16 + c2 - 1;
        bool valid = (hy >= 0) && (hy < HH) && (wx >= 0) && (wx < WW);
        uint4* dst = (uint4*)&lds[rr * 72];
        if (valid) {
            const uint4* src = (const uint4*)(xTb + ((size_t)(hy * WW + wx)) * 64);
#pragma unroll
            for (int ch = 0; ch < 8; ++ch) dst[ch] = src[ch];
        } else {
            uint4 z; z.x = z.y = z.z = z.w = 0;
#pragma unroll
            for (int ch = 0; ch < 8; ++ch) dst[ch] = z;
        }
    }
    __syncthreads();

    f32x4 acc[7][2];
#pragma unroll
    for (int mt = 0; mt < 7; ++mt)
#pragma unroll
        for (int i = 0; i < 2; ++i)
            acc[mt][i] = (f32x4){0.f, 0.f, 0.f, 0.f};

    const bf16x8* wAv = (const bf16x8*)wA;
    for (int kt = 0; kt < 18; ++kt) {
        int k = kt >> 1;
        int dh = k / 3, dw = k - dh * 3;
        int hh = kt & 1;
        bf16x8 bfrag[2];
#pragma unroll
        for (int i = 0; i < 2; ++i) {
            int nt = wv * 2 + i;
            int rr = (nt + dh) * 18 + lw + dw;
            bfrag[i] = *(const bf16x8*)&lds[rr * 72 + ((hh << 2) + kg) * 8];
        }
        bf16x8 afrag[7];
#pragma unroll
        for (int mt = 0; mt < 7; ++mt)
            afrag[mt] = wAv[(kt * 7 + mt) * 64 + lane];
#pragma unroll
        for (int mt = 0; mt < 7; ++mt)
#pragma unroll
            for (int i = 0; i < 2; ++i)
                acc[mt][i] = __builtin_amdgcn_mfma_f32_16x16x32_bf16(
                    afrag[mt], bfrag[i], acc[mt][i], 0, 0, 0);
    }

#pragma unroll
    for (int mt = 0; mt < 7; ++mt) {
#pragma unroll
        for (int r = 0; r < 4; ++r) {
            int m = mt * 16 + (kg << 2) + r;
            if (m < 108) {
                float bia = biasM[m];
#pragma unroll
                for (int i = 0; i < 2; ++i) {
                    int hgl = th * 8 + wv * 2 + i;
                    int wgl = tw * 16 + lw;
                    oaccb[((size_t)b * 108 + m) * HW + hgl * WW + wgl] =
                        f2bf(acc[mt][i][r] + bia);
                }
            }
        }
    }
}

// deformable conv as MFMA GEMM: out[64][256px] = W[64][576] * col[576][256px].
// grid 512: xcd = blk&7 -> (b = xcd>>2, quad = xcd&3); unit = blk>>3: tl = unit&15,
// g = unit>>4.  4 waves: wave wv owns N-tiles (px) wv*64..wv*64+63, all 4 M-tiles.
__global__ __launch_bounds__(256, 2) void dcn_mfma(const ushort_t* __restrict__ xT,
                                                   const ushort_t* __restrict__ oaccb,
                                                   const ushort_t* __restrict__ wA,
                                                   float* __restrict__ out) {
    int blk = blockIdx.x;
    int xcd = blk & 7;
    int b = xcd >> 2;
    int quad = xcd & 3;
    int unit = blk >> 3;
    int tl = unit & 15;
    int g = unit >> 4;
    int th = quad * 2 + (tl >> 3);
    int tw = tl & 7;
    int t = threadIdx.x;
    int wv = t >> 6, lane = t & 63;
    int lw = lane & 15, kg = lane >> 4;
    int h = th * 16 + (t >> 4);
    int w = tw * 16 + (t & 15);
    int px = h * WW + w;

    __shared__ ushort_t colLDS[256 * 72];   // 36 KB: row = pixel, 64 ch + 8 pad

    const ushort_t* xTb = xT + (size_t)b * HW * 64;
    const ushort_t* ob_in = oaccb + (size_t)(b * 4 + g) * 27 * HW + px;

    f32x4 acc[4][4];   // [mt][nt]
#pragma unroll
    for (int mt = 0; mt < 4; ++mt)
#pragma unroll
        for (int nt = 0; nt < 4; ++nt)
            acc[mt][nt] = (f32x4){0.f, 0.f, 0.f, 0.f};

    const bf16x8* wAv = (const bf16x8*)wA + (size_t)g * 4608;   // 18kt*4mt*64

    for (int k = 0; k < 9; ++k) {
        float dy = bfu(ob_in[(size_t)(2 * k) * HW]);
        float dx = bfu(ob_in[(size_t)(2 * k + 1) * HW]);
        float mk = 1.f / (1.f + expf(-bfu(ob_in[(size_t)(18 + k) * HW])));

        float py = (float)h + (float)(k / 3 - 1) + dy;
        float qx = (float)w + (float)(k % 3 - 1) + dx;
        float y0f = floorf(py), x0f = floorf(qx);
        float ly = py - y0f, lx = qx - x0f;
        int y0 = (int)y0f, x0 = (int)x0f;
        int y1 = y0 + 1, x1 = x0 + 1;

        bool vy0 = (y0 >= 0) && (y0 < HH), vy1 = (y1 >= 0) && (y1 < HH);
        bool vx0 = (x0 >= 0) && (x0 < WW), vx1 = (x1 >= 0) && (x1 < WW);
        int yc0 = min(max(y0, 0), HH - 1), yc1 = min(max(y1, 0), HH - 1);
        int xc0 = min(max(x0, 0), WW - 1), xc1 = min(max(x1, 0), WW - 1);
        int i00 = yc0 * WW + xc0, i01 = yc0 * WW + xc1;
        int i10 = yc1 * WW + xc0, i11 = yc1 * WW + xc1;

        float w00 = (1.f - ly) * (1.f - lx) * mk * ((vy0 && vx0) ? 1.f : 0.f);
        float w01 = (1.f - ly) * lx * mk * ((vy0 && vx1) ? 1.f : 0.f);
        float w10 = ly * (1.f - lx) * mk * ((vy1 && vx0) ? 1.f : 0.f);
        float w11 = ly * lx * mk * ((vy1 && vx1) ? 1.f : 0.f);

        // build this pixel's 64-channel col row in bf16
        uint_t* rowp = (uint_t*)&colLDS[t * 72];
        const uint4* p00 = (const uint4*)(xTb + (size_t)i00 * 64);
        const uint4* p01 = (const uint4*)(xTb + (size_t)i01 * 64);
        const uint4* p10 = (const uint4*)(xTb + (size_t)i10 * 64);
        const uint4* p11 = (const uint4*)(xTb + (size_t)i11 * 64);
#pragma unroll
        for (int qi = 0; qi < 8; ++qi) {
            uint4 u00 = p00[qi], u01 = p01[qi], u10 = p10[qi], u11 = p11[qi];
            uint_t e00[4] = {u00.x, u00.y, u00.z, u00.w};
            uint_t e01[4] = {u01.x, u01.y, u01.z, u01.w};
            uint_t e10[4] = {u10.x, u10.y, u10.z, u10.w};
            uint_t e11[4] = {u11.x, u11.y, u11.z, u11.w};
#pragma unroll
            for (int e = 0; e < 4; ++e) {
                float clo = w00 * bflo(e00[e]) + w01 * bflo(e01[e])
                          + w10 * bflo(e10[e]) + w11 * bflo(e11[e]);
                float chi = w00 * bfhi(e00[e]) + w01 * bfhi(e01[e])
                          + w10 * bfhi(e10[e]) + w11 * bfhi(e11[e]);
                rowp[qi * 4 + e] = pack2(clo, chi);
            }
        }
        __syncthreads();

#pragma unroll
        for (int kt2 = 0; kt2 < 2; ++kt2) {
            int kt = k * 2 + kt2;
            bf16x8 bfrag[4];
#pragma unroll
            for (int nt = 0; nt < 4; ++nt)
                bfrag[nt] = *(const bf16x8*)
                    &colLDS[(wv * 64 + nt * 16 + lw) * 72 + (kt2 * 4 + kg) * 8];
            bf16x8 afrag[4];
#pragma unroll
            for (int mt = 0; mt < 4; ++mt)
                afrag[mt] = wAv[(kt * 4 + mt) * 64 + lane];
#pragma unroll
            for (int mt = 0; mt < 4; ++mt)
#pragma unroll
                for (int nt = 0; nt < 4; ++nt)
                    acc[mt][nt] = __builtin_amdgcn_mfma_f32_16x16x32_bf16(
                        afrag[mt], bfrag[nt], acc[mt][nt], 0, 0, 0);
        }
        __syncthreads();
    }

    // epilogue: C/D col = lane&15 -> px, row = kg*4+r -> m; pixel shuffle store
    int s1 = g >> 1, s2 = g & 1;
#pragma unroll
    for (int mt = 0; mt < 4; ++mt) {
#pragma unroll
        for (int nt = 0; nt < 4; ++nt) {
            int pxl = wv * 64 + nt * 16 + lw;
            int hg = th * 16 + (pxl >> 4);
            int wg = tw * 16 + (pxl & 15);
            float* op = out + ((size_t)b * 64 + mt * 16 + (kg << 2)) * 65536
                      + (size_t)(hg * 2 + s1) * 256 + (wg * 2 + s2);
#pragma unroll
            for (int r = 0; r < 4; ++r)
                op[(size_t)r * 65536] = acc[mt][nt][r];
        }
    }
}

// per-channel sum/sumsq over out (pre-norm).  grid 64.
__global__ __launch_bounds__(256) void stats_sum(const float* __restrict__ out,
                                                 float* __restrict__ stats) {
    int o = blockIdx.x;
    int t = threadIdx.x;
    float s = 0.f, s2 = 0.f;
#pragma unroll
    for (int b = 0; b < 2; ++b) {
        const float* p = out + (size_t)b * 64 * 65536 + (size_t)o * 65536;
        for (int i = t * 4; i < 65536; i += 1024) {
            float4 v = *(const float4*)(p + i);
            s += v.x + v.y + v.z + v.w;
            s2 += v.x * v.x + v.y * v.y + v.z * v.z + v.w * v.w;
        }
    }
    __shared__ float red[512];
    red[t] = s;
    red[256 + t] = s2;
    __syncthreads();
#pragma unroll
    for (int m = 128; m >= 1; m >>= 1) {
        if (t < m) {
            red[t] += red[t + m];
            red[256 + t] += red[256 + t + m];
        }
        __syncthreads();
    }
    if (t == 0) {
        stats[o] = red[0];
        stats[64 + o] = red[256];
    }
}

__global__ void finalize(const float* __restrict__ stats,
                         const float* __restrict__ gamma,
                         const float* __restrict__ beta,
                         float* __restrict__ ab) {
    int t = threadIdx.x;
    if (t < 64) {
        float mean = stats[t] / NVALS;
        float var = stats[64 + t] / NVALS - mean * mean;
        var = fmaxf(var, 0.f);
        float a = gamma[t] * rsqrtf(var + 1e-5f);
        ab[t] = a;
        ab[64 + t] = beta[t] - mean * a;
    }
}

__global__ void norm_relu(float* __restrict__ out, const float* __restrict__ ab) {
    size_t tid = (size_t)blockIdx.x * 256 + threadIdx.x;
    size_t base = tid * 4;
    int o = (int)((base >> 16) & 63);
    float a = ab[o], bb = ab[64 + o];
    float4* p = (float4*)(out + base);
    float4 v = *p;
    v.x = fmaxf(fmaf(v.x, a, bb), 0.f);
    v.y = fmaxf(fmaf(v.y, a, bb), 0.f);
    v.z = fmaxf(fmaf(v.z, a, bb), 0.f);
    v.w = fmaxf(fmaf(v.w, a, bb), 0.f);
    *p = v;
}

extern "C" void kernel_launch(void* const* d_in, const int* in_sizes, int n_in,
                              void* d_out, int out_size, void* d_ws, size_t ws_size,
                              hipStream_t stream) {
    const float* x        = (const float*)d_in[0];
    const float* w_offset = (const float*)d_in[1];
    const float* b_offset = (const float*)d_in[2];
    const float* w_dcn    = (const float*)d_in[3];
    const float* gamma    = (const float*)d_in[4];
    const float* beta     = (const float*)d_in[5];
    float* out            = (float*)d_out;
    float* ws = (float*)d_ws;

    prep<<<576, 256, 0, stream>>>(w_offset, b_offset, w_dcn, ws);
    transpose_x<<<512, 256, 0, stream>>>(x, (ushort_t*)(ws + XT));
    conv_mfma<<<256, 256, 0, stream>>>((ushort_t*)(ws + XT), (ushort_t*)(ws + WACONV),
                                       ws + BIAS2, (ushort_t*)(ws + OACC));
    dcn_mfma<<<512, 256, 0, stream>>>((ushort_t*)(ws + XT), (ushort_t*)(ws + OACC),
                                      (ushort_t*)(ws + WADCN), out);
    stats_sum<<<64, 256, 0, stream>>>(out, ws + STATS);
    finalize<<<1, 64, 0, stream>>>(ws + STATS, gamma, beta, ws + STATS + 128);
    norm_relu<<<8192, 256, 0, stream>>>(out, ws + STATS + 128);
}